// Round 17
// baseline (59.666 us; speedup 1.0000x reference)
//
#include <hip/hip_runtime.h>
#include <math.h>

#define N_NODES 8192
#define N_EDGES 262144
#define NFEAT 128
#define NHID 256
#define NCLASS 16
#define ELLS 96   // ELL stride; P(Poisson(32) >= 96) ~ 1e-18 per row

// LESSON (round 13): grid.sync() mega-kernel = ~58 us PER SYNC at 512 blocks. Never.
// LESSON (round 15): dependent loads (deg[c]) in the gather staging chain cost
// ~10 us. Normalization stays pre-folded: xs carries di[c], V2s carries di[c].
// LESSON (round 16): gather kernels were grid-limited (16/8 waves per CU);
// widen threads-per-row to reach 32 waves/CU.

// f32 -> bf16 with round-to-nearest-even
__device__ inline unsigned int f2bf(float f) {
    unsigned int u = __float_as_uint(f);
    u += 0x7fffu + ((u >> 16) & 1u);
    return u >> 16;
}
__device__ inline float bf_lo(unsigned int u) { return __uint_as_float(u << 16); }
__device__ inline float bf_hi(unsigned int u) { return __uint_as_float(u & 0xffff0000u); }

// ---------------- zero cnt (32 KB) ----------------
__global__ void zero_kernel(int* __restrict__ p) {
    p[blockIdx.x * 256 + threadIdx.x] = 0;   // 32 blocks x 256 = 8192 words
}

// ---------------- one pass over edges: count + ELL store (raw weight) ----------------
__global__ __launch_bounds__(256) void histscatter_kernel(const int* __restrict__ ei,
                                                          const float* __restrict__ ew,
                                                          int* __restrict__ cnt,
                                                          int2* __restrict__ ell) {
    int e = blockIdx.x * 256 + threadIdx.x;     // 1024 blocks == E exactly
    int r = ei[e];
    int c = ei[N_EDGES + e];
    float w = ew[e];
    int slot = atomicAdd(&cnt[r], 1);
    ell[r * ELLS + slot] = make_int2(c, __float_as_int(w));
}

// ---------------- per row: deg, dinv, xs = bf16(dinv*x). 8 rows/block, 32 lanes/row ----------------
__global__ __launch_bounds__(256) void dinvcvt_kernel(const int* __restrict__ cnt,
                                                      const int2* __restrict__ ell,
                                                      const float* __restrict__ x,
                                                      float* __restrict__ dinv,
                                                      uint2* __restrict__ xs) {
    int t = threadIdx.x;
    int lane = t & 31;
    int r = blockIdx.x * 8 + (t >> 5);          // 1024 blocks
    int n = cnt[r];
    float sum = 0.0f;
    for (int base = 0; base < n; base += 32) {
        int idx = base + lane;
        if (idx < n) sum += __int_as_float(ell[r * ELLS + idx].y);
    }
    #pragma unroll
    for (int off = 1; off < 32; off <<= 1) sum += __shfl_xor(sum, off, 32);
    float di = rsqrtf(sum + 1.0f);              // + self loop, always >= 1
    if (lane == 0) dinv[r] = di;
    float4 a = ((const float4*)(x + (size_t)r * NFEAT + lane * 4))[0];
    uint2 o;
    o.x = f2bf(di * a.x) | (f2bf(di * a.y) << 16);
    o.y = f2bf(di * a.z) | (f2bf(di * a.w) << 16);
    xs[r * 32 + lane] = o;
}

// ---------------- fused: gather -> AX -> H=relu(AX@W1+b1) -> V2s=dinv*(H@W2) ----------------
// 512 threads, 8 rows/block, 64 lanes/row, 1024 blocks -> 32 waves/CU (max).
// LDS 22.2 KB; phase B k-split in halves with LDS partial; phase C k-split x4.
__global__ __launch_bounds__(512) void layer12_kernel(const int* __restrict__ cnt,
                                                      const int2* __restrict__ ell,
                                                      const unsigned int* __restrict__ xs1,
                                                      const float* __restrict__ dinv,
                                                      const float* __restrict__ W1,
                                                      const float* __restrict__ b1,
                                                      const float* __restrict__ W2,
                                                      float* __restrict__ V2s) {
    __shared__ float axs[8][NFEAT];        // 4 KB
    __shared__ float psum[8][NHID];        // 8 KB
    __shared__ float hs[8][NHID + 4];      // 8.125 KB
    __shared__ float part[512];            // 2 KB
    int t = threadIdx.x;

    // ---- phase A: acc = xs[r] + sum w*xs[c]; AX = dinv[r]*acc. 2 bf16/lane.
    int lane = t & 63;
    int rloc = t >> 6;
    int r = blockIdx.x * 8 + rloc;
    int n = cnt[r];
    float di = dinv[r];
    unsigned int xv = xs1[r * 64 + lane];
    float acc0 = bf_lo(xv), acc1 = bf_hi(xv);   // self (xs already dinv-scaled)
    for (int base = 0; base < n; base += 16) {
        int idx = base + (lane & 15);
        int2 cw = ell[r * ELLS + idx];
        int cc = cw.x & (N_NODES - 1);          // clamp garbage tail
        float wl = __int_as_float(cw.y);
        wl = (idx < n) ? wl : 0.0f;             // mask folded pre-broadcast
        #pragma unroll
        for (int u = 0; u < 16; ++u) {
            int c = __shfl(cc, u, 16);
            float w = __shfl(wl, u, 16);
            unsigned int v = xs1[c * 64 + lane];
            acc0 += w * bf_lo(v);
            acc1 += w * bf_hi(v);
        }
    }
    ((float2*)&axs[rloc][lane * 2])[0] = make_float2(di * acc0, di * acc1);
    __syncthreads();

    // ---- phase B: k-split halves. col = t&255, kh = t>>8.
    int col = t & 255;
    int kh = t >> 8;
    float hacc[8];
    #pragma unroll
    for (int q = 0; q < 8; ++q) hacc[q] = 0.0f;
    int k0 = kh * 64;
    #pragma unroll 4
    for (int k = k0; k < k0 + 64; ++k) {
        float w = W1[k * NHID + col];
        #pragma unroll
        for (int q = 0; q < 8; ++q) hacc[q] += axs[q][k] * w;
    }
    if (kh == 0) {
        #pragma unroll
        for (int q = 0; q < 8; ++q) psum[q][col] = hacc[q];
    }
    __syncthreads();
    if (kh == 1) {
        float bb = b1[col];
        #pragma unroll
        for (int q = 0; q < 8; ++q) {
            float v = psum[q][col] + hacc[q] + bb;
            hs[q][col] = v > 0.0f ? v : 0.0f;
        }
    }
    __syncthreads();

    // ---- phase C: V2s[r][j] = dinv[r] * sum_k hs[r][k] * W2[k][j]; k-split x4.
    int j = t & 15;
    int rq = (t >> 4) & 7;
    int kb = (t >> 7) * 64;                     // 4 quarters of 64
    float p = 0.0f;
    #pragma unroll 8
    for (int k = 0; k < 64; ++k) p += hs[rq][kb + k] * W2[(kb + k) * NCLASS + j];
    part[t] = p;
    __syncthreads();
    if (t < 128) {
        int rg = blockIdx.x * 8 + (t >> 4);
        V2s[rg * NCLASS + (t & 15)] =
            dinv[rg] * (part[t] + part[t + 128] + part[t + 256] + part[t + 384]);
    }
}

// ---------------- out[r] = log_softmax(dinv[r]*(V2s[r] + sum w*V2s[c]) + b2) ----------------
// 8 rows/block, 32 lanes/row (two 16-lane groups on alternate chunks), 1024 blocks.
// V2s already carries di[c]; weights RAW here (round-14 lesson).
__global__ __launch_bounds__(256) void agg2_kernel(const int* __restrict__ cnt,
                                                   const int2* __restrict__ ell,
                                                   const float* __restrict__ V2s,
                                                   const float* __restrict__ dinv,
                                                   const float* __restrict__ b2,
                                                   float* __restrict__ out) {
    int t = threadIdx.x;
    int lane = t & 31;
    int g = lane >> 4;                // half: alternate chunks
    int j = lane & 15;                // class
    int r = blockIdx.x * 8 + (t >> 5);
    int n = cnt[r];
    float di = dinv[r];
    float acc = (g == 0) ? V2s[r * NCLASS + j] : 0.0f;   // self term once
    for (int base = g * 16; base < n; base += 32) {
        int idx = base + j;
        int2 cw = ell[r * ELLS + idx];
        int cc = cw.x & (N_NODES - 1);
        float wl = __int_as_float(cw.y);
        wl = (idx < n) ? wl : 0.0f;
        #pragma unroll
        for (int u = 0; u < 16; ++u) {
            int c = __shfl(cc, u, 16);
            float w = __shfl(wl, u, 16);
            acc += w * V2s[c * NCLASS + j];
        }
    }
    acc += __shfl_xor(acc, 16, 32);   // combine the two chunk-groups
    float v = di * acc + b2[j];
    // log_softmax across 16 lanes (both halves hold identical values)
    float mx = v;
    #pragma unroll
    for (int off = 1; off < 16; off <<= 1) mx = fmaxf(mx, __shfl_xor(mx, off));
    float ex = expf(v - mx);
    float ssum = ex;
    #pragma unroll
    for (int off = 1; off < 16; off <<= 1) ssum += __shfl_xor(ssum, off);
    if (g == 0) out[r * NCLASS + j] = v - mx - logf(ssum);
}

extern "C" void kernel_launch(void* const* d_in, const int* in_sizes, int n_in,
                              void* d_out, int out_size, void* d_ws, size_t ws_size,
                              hipStream_t stream) {
    const float* x  = (const float*)d_in[0];
    const int*   ei = (const int*)d_in[1];      // [2, E] flat: row = ei[e], col = ei[E+e]
    const float* ew = (const float*)d_in[2];
    const float* W1 = (const float*)d_in[3];
    const float* b1 = (const float*)d_in[4];
    const float* W2 = (const float*)d_in[5];
    const float* b2 = (const float*)d_in[6];
    float* out = (float*)d_out;

    const int n = N_NODES;

    char* ws = (char*)d_ws;
    int*   cnt  = (int*)  (ws);                  // [0, 32K)
    float* dinv = (float*)(ws + 32768);          // [32K, 64K)
    int2*  ell  = (int2*) (ws + 65536);          // [64K, 64K+6M): 8192*96*8 B
    float* V2s  = (float*)(ws + 8388608);        // [8M, 8.5M)
    uint2* xs   = (uint2*)(ws + 16777216);       // [16M, 18M): bf16 dinv-scaled x

    zero_kernel<<<32, 256, 0, stream>>>(cnt);

    histscatter_kernel<<<N_EDGES / 256, 256, 0, stream>>>(ei, ew, cnt, ell);
    dinvcvt_kernel<<<n / 8, 256, 0, stream>>>(cnt, ell, x, dinv, xs);

    layer12_kernel<<<n / 8, 512, 0, stream>>>(cnt, ell, (const unsigned int*)xs,
                                              dinv, W1, b1, W2, V2s);
    agg2_kernel<<<n / 8, 256, 0, stream>>>(cnt, ell, V2s, dinv, b2, out);
}